// Round 3
// baseline (939.764 us; speedup 1.0000x reference)
//
#include <hip/hip_runtime.h>

// LSTM, T=2048, B=2048, IN=5, H=10, fp32. Output [T*B, H].
// Latency-bound on the per-step serial recurrence -> minimize critical path.
// This version has ZERO LDS instructions:
//   - 16 lanes per batch (one DPP row). lane j<10 owns hidden unit j and
//     computes all 4 of its gates (i,f,g,o); lanes 10..15 are spares whose
//     weight columns are zero.
//   - h "broadcast" is a systolic DPP row rotation: 4 parallel rotation
//     chains seeded by row_ror:4/8/12 (chain depth ~4 movs), each feeding
//     packed v_pk_fma_f32 accumulators (8 accs -> FMA dep chains of 4).
//     DPP semantics: row_ror:N => dst[i] = src[(i-N) & 15], so after s
//     ror:1 steps lane j holds h_{(j-s)&15}; weight tables indexed to match.
//   - cell update is lane-local; only vmem ops are the x prefetch ring
//     (PF=8 steps ahead) and the h store.
// 4 batches per wave, 512 blocks x 64 threads.

#define T_STEPS 2048
#define BATCH   2048
#define NIN     5
#define NH      10
#define PF      8
#define GPW     4    // batches per wave (16 lanes each)

typedef float v2f __attribute__((ext_vector_type(2)));

__device__ __forceinline__ float hw_exp2(float v) { return __builtin_amdgcn_exp2f(v); }
__device__ __forceinline__ float hw_rcp(float v)  { return __builtin_amdgcn_rcpf(v); }
__device__ __forceinline__ v2f splat2(float v) { v2f r; r.x = v; r.y = v; return r; }

// DPP permute within 16-lane rows. row_ror:N = 0x120+N.
template<int CTRL>
__device__ __forceinline__ float dpp_f(float v) {
    int i = __builtin_bit_cast(int, v);
    return __builtin_bit_cast(float,
        __builtin_amdgcn_update_dpp(i, i, CTRL, 0xF, 0xF, false));
}

__global__ __launch_bounds__(64) void lstm_fused_kernel(
    const float* __restrict__ x,   const float* __restrict__ hx0,
    const float* __restrict__ cx0, const float* __restrict__ Wih,
    const float* __restrict__ Whh, const float* __restrict__ bih,
    const float* __restrict__ bhh, float* __restrict__ out)
{
    const float L2E  = 1.4426950408889634f;   // log2(e)
    const float L2E2 = 2.8853900817779268f;   // 2*log2(e)

    const int lane = threadIdx.x;
    const int row  = lane >> 4;        // batch slot in wave: 0..3
    const int j    = lane & 15;        // unit 0..9 active, 10..15 spare
    const int b    = blockIdx.x * GPW + row;     // always < 2048 (512*4)
    const int jc   = (j < NH) ? j : (NH - 1);    // clamped for loads
    const bool act = (j < NH);

    // torch LSTMCell gate rows: i:[0,10) f:[10,20) g:[20,30) o:[30,40)
    const int ri = jc, rf = NH + jc, rg = 2 * NH + jc, ro = 3 * NH + jc;

    // x weights + bias, packed (i,f)/(g,o).
    v2f wxif[NIN], wxgo[NIN];
#pragma unroll
    for (int k = 0; k < NIN; ++k) {
        wxif[k].x = Wih[ri * NIN + k];  wxif[k].y = Wih[rf * NIN + k];
        wxgo[k].x = Wih[rg * NIN + k];  wxgo[k].y = Wih[ro * NIN + k];
    }
    v2f bif, bgo;
    bif.x = bih[ri] + bhh[ri];  bif.y = bih[rf] + bhh[rf];
    bgo.x = bih[rg] + bhh[rg];  bgo.y = bih[ro] + bhh[ro];

    // Recurrent weights indexed by rotation step s: at step s this lane sees
    // h of unit u = (j - s) & 15; zero weight for padded units u >= 10.
    v2f whif_s[16], whgo_s[16];
#pragma unroll
    for (int s = 0; s < 16; ++s) {
        const int u = (j - s) & 15;
        if (u < NH) {
            whif_s[s].x = Whh[ri * NH + u];  whif_s[s].y = Whh[rf * NH + u];
            whgo_s[s].x = Whh[rg * NH + u];  whgo_s[s].y = Whh[ro * NH + u];
        } else {
            whif_s[s] = splat2(0.0f);
            whgo_s[s] = splat2(0.0f);
        }
    }

    float h   = hx0[b * NH + jc];   // this lane's unit's h (spares: dup of 9)
    float cst = cx0[b * NH + jc];   // lane-local cell state

    // PF-deep x prefetch ring (all 16 lanes of a row load the same 5 floats).
    const float* xb = x + (size_t)b * NIN;
    float xr[PF][NIN];
#pragma unroll
    for (int q = 0; q < PF; ++q)
#pragma unroll
        for (int k = 0; k < NIN; ++k)
            xr[q][k] = xb[(size_t)q * (BATCH * NIN) + k];

    float* outp = out + (size_t)b * NH + j;

#pragma unroll 1
    for (int t0 = 0; t0 < T_STEPS; t0 += PF) {
#pragma unroll
        for (int q = 0; q < PF; ++q) {
            const int t = t0 + q;

            // 8 packed accumulators -> no FMA dep chain deeper than ~4.
            v2f a0 = bif,          g0 = bgo;
            v2f a1 = splat2(0.f),  g1 = splat2(0.f);
            v2f a2 = splat2(0.f),  g2 = splat2(0.f);
            v2f a3 = splat2(0.f),  g3 = splat2(0.f);

            // ---- x-dot (independent of h -> fills rotation-wait slots) ----
            {
                v2f x0 = splat2(xr[q][0]), x1 = splat2(xr[q][1]),
                    x2 = splat2(xr[q][2]), x3 = splat2(xr[q][3]),
                    x4 = splat2(xr[q][4]);
                a0 += x0 * wxif[0];  g0 += x0 * wxgo[0];
                a1 += x1 * wxif[1];  g1 += x1 * wxgo[1];
                a2 += x2 * wxif[2];  g2 += x2 * wxgo[2];
                a3 += x3 * wxif[3];  g3 += x3 * wxgo[3];
                a0 += x4 * wxif[4];  g0 += x4 * wxgo[4];
            }

            // refill consumed ring slot with x(t+PF) (clamped at tail)
            {
                int tn = t + PF;
                if (tn > T_STEPS - 1) tn = T_STEPS - 1;
#pragma unroll
                for (int k = 0; k < NIN; ++k)
                    xr[q][k] = xb[(size_t)tn * (BATCH * NIN) + k];
            }

            // ---- h-dot via 4 parallel DPP rotation chains ----
            float r0 = h;                  // s = 0..3
            float r1 = dpp_f<0x124>(h);    // ror:4,  s = 4..7
            float r2 = dpp_f<0x128>(h);    // ror:8,  s = 8..11
            float r3 = dpp_f<0x12C>(h);    // ror:12, s = 12..15
#pragma unroll
            for (int s = 0; s < 4; ++s) {
                v2f h0 = splat2(r0), h1 = splat2(r1),
                    h2 = splat2(r2), h3 = splat2(r3);
                a0 += h0 * whif_s[s];       g0 += h0 * whgo_s[s];
                a1 += h1 * whif_s[s + 4];   g1 += h1 * whgo_s[s + 4];
                a2 += h2 * whif_s[s + 8];   g2 += h2 * whgo_s[s + 8];
                a3 += h3 * whif_s[s + 12];  g3 += h3 * whgo_s[s + 12];
                if (s < 3) {
                    r0 = dpp_f<0x121>(r0);  // ror:1
                    r1 = dpp_f<0x121>(r1);
                    r2 = dpp_f<0x121>(r2);
                    r3 = dpp_f<0x121>(r3);
                }
            }
            const v2f aif = (a0 + a1) + (a2 + a3);
            const v2f ago = (g0 + g1) + (g2 + g3);

            // ---- lane-local nonlinearities + cell update ----
            const float si = hw_rcp(1.0f + hw_exp2(-L2E  * aif.x));
            const float sf = hw_rcp(1.0f + hw_exp2(-L2E  * aif.y));
            const float tg = fmaf(2.0f, hw_rcp(1.0f + hw_exp2(-L2E2 * ago.x)), -1.0f);
            const float so = hw_rcp(1.0f + hw_exp2(-L2E  * ago.y));

            cst = fmaf(sf, cst, si * tg);            // c' = sig(f)*c + sig(i)*tanh(g)
            const float tc = fmaf(2.0f, hw_rcp(1.0f + hw_exp2(-L2E2 * cst)), -1.0f);
            h = so * tc;                             // h' = sig(o)*tanh(c')

            if (act) outp[(size_t)t * (BATCH * NH)] = h;
        }
    }
}

extern "C" void kernel_launch(void* const* d_in, const int* in_sizes, int n_in,
                              void* d_out, int out_size, void* d_ws, size_t ws_size,
                              hipStream_t stream) {
    const float* x   = (const float*)d_in[0];
    const float* hx0 = (const float*)d_in[1];
    const float* cx0 = (const float*)d_in[2];
    const float* Wih = (const float*)d_in[3];
    const float* Whh = (const float*)d_in[4];
    const float* bih = (const float*)d_in[5];
    const float* bhh = (const float*)d_in[6];
    float* out = (float*)d_out;

    const int nblocks = BATCH / GPW;   // 512 blocks x 64 threads
    lstm_fused_kernel<<<nblocks, 64, 0, stream>>>(x, hx0, cx0, Wih, Whh, bih, bhh, out);
}